// Round 3
// baseline (913.004 us; speedup 1.0000x reference)
//
#include <hip/hip_runtime.h>
#include <hip/hip_bf16.h>
#include <stdint.h>

typedef unsigned short u16;
typedef __attribute__((ext_vector_type(8))) short short8;
typedef __attribute__((ext_vector_type(4))) float floatx4;

#define DIM    2048
#define HEADS  16
#define DHEAD  128
#define BB     4
#define NSEQ   1024
#define JSEQ   2048
#define NIN    6144
#define KVOFF  ((size_t)8388608)   // cached_kv element offset inside d_out

__device__ __forceinline__ float bf2f(u16 u) {
  union { uint32_t u; float f; } c; c.u = ((uint32_t)u) << 16; return c.f;
}
__device__ __forceinline__ u16 f2bf(float f) {
  union { float f; uint32_t u; } c; c.f = f;
  uint32_t u = c.u;
  return (u16)((u + 0x7fffu + ((u >> 16) & 1u)) >> 16);
}
__device__ __forceinline__ float ldw(const void* p, size_t i, int isf) {
  if (isf) return ((const float*)p)[i];
  return bf2f(((const u16*)p)[i]);
}
__device__ __forceinline__ void stw(void* p, size_t i, int isf, float v) {
  if (isf) ((float*)p)[i] = v;
  else     ((u16*)p)[i] = f2bf(v);
}

// async global->LDS, 16B per lane. LDS dest must be wave-uniform base (+lane*16 implicit).
__device__ __forceinline__ void gload16(const u16* g, u16* l) {
  __builtin_amdgcn_global_load_lds(
      reinterpret_cast<const __attribute__((address_space(1))) void*>(
          reinterpret_cast<uintptr_t>(g)),
      reinterpret_cast<__attribute__((address_space(3))) void*>(
          reinterpret_cast<uintptr_t>(l)),
      16, 0, 0);
}

__global__ void detect_k(const void* normw, int* flag) {
  uint32_t v = *(const uint32_t*)normw;
  *flag = ((v & 0xFFFFu) == 0u) ? 1 : 0;   // fp32 1.0f low16==0; bf16 pair low16=0x3F80
}

__global__ __launch_bounds__(256) void rmsnorm_k(const void* __restrict__ x,
                                                 const void* __restrict__ w,
                                                 u16* __restrict__ xn,
                                                 const int* __restrict__ flag)
{
  const int isf = *flag;
  const int row = blockIdx.x;
  const int t = threadIdx.x;
  const size_t base = (size_t)row * DIM + t * 8;
  float f[8]; float ss = 0.f;
  #pragma unroll
  for (int i = 0; i < 8; ++i) { f[i] = ldw(x, base + i, isf); ss += f[i] * f[i]; }
  #pragma unroll
  for (int off = 1; off < 64; off <<= 1) ss += __shfl_xor(ss, off, 64);
  __shared__ float red[4];
  if ((t & 63) == 0) red[t >> 6] = ss;
  __syncthreads();
  float tot = red[0] + red[1] + red[2] + red[3];
  float rs = rsqrtf(tot * (1.0f / DIM) + 1.1920929e-7f);
  #pragma unroll
  for (int i = 0; i < 8; ++i)
    xn[base + i] = f2bf(f[i] * rs * ldw(w, (size_t)(t * 8 + i), isf));
}

// Transpose + convert weights: W[K][N] (wire) -> WT[N][K] (bf16). 64x64 tiles.
__global__ __launch_bounds__(256) void prep_w_k(const void* __restrict__ W,
                                                u16* __restrict__ WT,
                                                const int* __restrict__ flag,
                                                int K, int N)
{
  __shared__ u16 T[64][72];
  const int isf = *flag;
  const int n0 = blockIdx.x * 64, k0 = blockIdx.y * 64;
  const int tid = threadIdx.x;
  const int r = tid >> 2;           // 0..63
  const int c = (tid & 3) * 16;     // 0,16,32,48
  {
    u16 tmp[16];
    if (isf) {
      const float4* p = (const float4*)((const float*)W + (size_t)(k0 + r) * N + n0 + c);
      #pragma unroll
      for (int cc = 0; cc < 4; ++cc) {
        const float4 fv = p[cc];
        tmp[cc * 4 + 0] = f2bf(fv.x);
        tmp[cc * 4 + 1] = f2bf(fv.y);
        tmp[cc * 4 + 2] = f2bf(fv.z);
        tmp[cc * 4 + 3] = f2bf(fv.w);
      }
    } else {
      const uint4* p = (const uint4*)((const u16*)W + (size_t)(k0 + r) * N + n0 + c);
      *(uint4*)&tmp[0] = p[0];
      *(uint4*)&tmp[8] = p[1];
    }
    #pragma unroll
    for (int e = 0; e < 16; ++e) T[r][c + e] = tmp[e];
  }
  __syncthreads();
  {
    u16 tmp[16];
    #pragma unroll
    for (int e = 0; e < 16; ++e) tmp[e] = T[c + e][r];
    uint4* q = (uint4*)(WT + (size_t)(n0 + r) * K + k0 + c);
    q[0] = *(const uint4*)&tmp[0];
    q[1] = *(const uint4*)&tmp[8];
  }
}

// V[bh][j][d] (wire, inside dout) -> VT[bh][d][j] (bf16). 64x64 tiles.
__global__ __launch_bounds__(256) void v_tr_k(const void* __restrict__ dout,
                                              u16* __restrict__ vt,
                                              const int* __restrict__ flag)
{
  __shared__ u16 T[64][72];
  const int isf = *flag;
  const int j0 = blockIdx.x * 64;        // 0..2047
  const int d0 = blockIdx.y * 64;        // 0,64
  const int bh = blockIdx.z;             // 0..63
  const int b = bh >> 4, h = bh & 15;
  const size_t vbase = KVOFF + (((size_t)b * 2 + 1) * HEADS + h) * JSEQ * DHEAD;
  const int tid = threadIdx.x;
  const int r = tid >> 2;
  const int c = (tid & 3) * 16;
  {
    u16 tmp[16];
    if (isf) {
      const float4* p = (const float4*)((const float*)dout + vbase + (size_t)(j0 + r) * DHEAD + d0 + c);
      #pragma unroll
      for (int cc = 0; cc < 4; ++cc) {
        const float4 fv = p[cc];
        tmp[cc * 4 + 0] = f2bf(fv.x);
        tmp[cc * 4 + 1] = f2bf(fv.y);
        tmp[cc * 4 + 2] = f2bf(fv.z);
        tmp[cc * 4 + 3] = f2bf(fv.w);
      }
    } else {
      const uint4* p = (const uint4*)((const u16*)dout + vbase + (size_t)(j0 + r) * DHEAD + d0 + c);
      *(uint4*)&tmp[0] = p[0];
      *(uint4*)&tmp[8] = p[1];
    }
    #pragma unroll
    for (int e = 0; e < 16; ++e) T[r][c + e] = tmp[e];
  }
  __syncthreads();
  {
    u16 tmp[16];
    #pragma unroll
    for (int e = 0; e < 16; ++e) tmp[e] = T[c + e][r];
    uint4* q = (uint4*)(vt + ((size_t)bh * DHEAD + d0 + r) * JSEQ + j0 + c);
    q[0] = *(const uint4*)&tmp[0];
    q[1] = *(const uint4*)&tmp[8];
  }
}

// C = A[M,K](bf16) x BT[N,K](bf16)^T. m97 structure: global_load_lds + ds_read_b128.
// mode 0: C -> obuf (wire). mode 1: qkv split.
__global__ __launch_bounds__(256) void gemm_tn(const u16* __restrict__ A,
                                               const u16* __restrict__ BT,
                                               void* __restrict__ obuf,
                                               u16* __restrict__ qbuf,
                                               void* __restrict__ dout,
                                               const int* __restrict__ flag,
                                               int M, int N, int K, int mode)
{
  __shared__ __align__(16) u16 As[128 * 32];
  __shared__ __align__(16) u16 Bs[128 * 32];
  const int isf = *flag;
  const int tid = threadIdx.x;
  const int lane = tid & 63;
  const int w = tid >> 6;
  const int wm = w & 1, wn = w >> 1;
  const int l15 = lane & 15, quad = lane >> 4;
  const int m0 = blockIdx.y * 128, n0 = blockIdx.x * 128;

  const int srow = tid >> 2;          // 0..63
  const int scol = (tid & 3) * 8;     // 0,8,16,24
  const u16* ag0 = A  + (size_t)(m0 + srow) * K + scol;
  const u16* ag1 = A  + (size_t)(m0 + 64 + srow) * K + scol;
  const u16* bg0 = BT + (size_t)(n0 + srow) * K + scol;
  const u16* bg1 = BT + (size_t)(n0 + 64 + srow) * K + scol;
  u16* const al = As + w * 512;       // wave-uniform LDS base (+lane*16B implicit)
  u16* const bl = Bs + w * 512;

  floatx4 acc[4][4];
  #pragma unroll
  for (int i = 0; i < 4; ++i)
    #pragma unroll
    for (int j = 0; j < 4; ++j) acc[i][j] = (floatx4){0.f, 0.f, 0.f, 0.f};

  for (int k0 = 0; k0 < K; k0 += 32) {
    __syncthreads();
    gload16(ag0 + k0, al);
    gload16(ag1 + k0, al + 2048);
    gload16(bg0 + k0, bl);
    gload16(bg1 + k0, bl + 2048);
    __syncthreads();

    short8 af[4], bfr[4];
    #pragma unroll
    for (int mt = 0; mt < 4; ++mt)
      af[mt] = *(const short8*)&As[(wm * 64 + mt * 16 + l15) * 32 + quad * 8];
    #pragma unroll
    for (int nt = 0; nt < 4; ++nt)
      bfr[nt] = *(const short8*)&Bs[(wn * 64 + nt * 16 + l15) * 32 + quad * 8];
    __builtin_amdgcn_s_setprio(1);
    #pragma unroll
    for (int mt = 0; mt < 4; ++mt)
      #pragma unroll
      for (int nt = 0; nt < 4; ++nt)
        acc[mt][nt] = __builtin_amdgcn_mfma_f32_16x16x32_bf16(af[mt], bfr[nt], acc[mt][nt], 0, 0, 0);
    __builtin_amdgcn_s_setprio(0);
  }

  #pragma unroll
  for (int mt = 0; mt < 4; ++mt)
    #pragma unroll
    for (int nt = 0; nt < 4; ++nt) {
      const int col = n0 + wn * 64 + nt * 16 + l15;
      #pragma unroll
      for (int r = 0; r < 4; ++r) {
        const int row = m0 + wm * 64 + mt * 16 + quad * 4 + r;
        const float v = acc[mt][nt][r];
        if (mode == 0) {
          stw(obuf, (size_t)row * N + col, isf, v);
        } else {
          const int b = row >> 10, i = row & 1023;
          const int sec = col >> 11, within = col & 2047;
          const int h = within >> 7, d = within & 127;
          if (sec == 0) {
            qbuf[(((size_t)(b * HEADS + h)) * NSEQ + i) * DHEAD + d] = f2bf(v);
          } else {
            const size_t idx = KVOFF +
              ((((size_t)b * 2 + (sec - 1)) * HEADS + h) * JSEQ + NSEQ + i) * DHEAD + d;
            stw(dout, idx, isf, v);
          }
        }
      }
    }
}

__global__ __launch_bounds__(256) void copy_cache_k(const void* __restrict__ cache,
                                                    void* __restrict__ dout,
                                                    const int* __restrict__ flag)
{
  const int isf = *flag;
  const size_t t = ((size_t)blockIdx.x * 256 + threadIdx.x) * 4;   // element index
  const size_t sh = t >> 17;
  const size_t rem = t & 131071;
  const size_t dst = KVOFF + (sh << 18) + rem;
  if (isf) *(float4*)((float*)dout + dst) = *(const float4*)((const float*)cache + t);
  else     *(uint2*)((u16*)dout + dst)    = *(const uint2*)((const u16*)cache + t);
}

// One-shot: rotate full K (cached + new) into bf16 krot[b][h][JSEQ][DHEAD].
__global__ __launch_bounds__(256) void k_rot_k(const void* __restrict__ dout,
                                               const void* __restrict__ rote,
                                               u16* __restrict__ krot,
                                               const int* __restrict__ flag)
{
  const int isf = *flag;
  const size_t t = (size_t)blockIdx.x * 256 + threadIdx.x;   // 8,388,608
  const int d = (int)(t & 63);
  const size_t row = t >> 6;                    // bh*JSEQ + j
  const int j = (int)(row & (JSEQ - 1));
  const size_t bh = row >> 11;                  // b*16 + h
  const size_t kb = KVOFF + (((bh >> 4) * 2 * HEADS + (bh & 15)) * (size_t)JSEQ + j) * DHEAD;
  const float k1 = ldw(dout, kb + d, isf);
  const float k2 = ldw(dout, kb + d + 64, isf);
  const size_t rb = (size_t)j * DHEAD;
  const float p1 = ldw(rote, rb + d, isf);
  const float p2 = ldw(rote, rb + d + 64, isf);
  krot[row * DHEAD + d]      = f2bf(k1 * cosf(p1) - k2 * sinf(p1));
  krot[row * DHEAD + d + 64] = f2bf(k2 * cosf(p2) + k1 * sinf(p2));
}

__global__ __launch_bounds__(256) void q_rot_k(u16* __restrict__ q,
                                               const void* __restrict__ rote,
                                               const int* __restrict__ flag)
{
  const int isf = *flag;
  const size_t t = (size_t)blockIdx.x * 256 + threadIdx.x;   // 4,194,304
  const int d = (int)(t & 63);
  const size_t row = t >> 6;
  const int i = (int)(row & 1023);
  const size_t qbase = row * DHEAD;
  const size_t rbase = (size_t)(NSEQ + i) * DHEAD;
  const float q1 = bf2f(q[qbase + d]);
  const float q2 = bf2f(q[qbase + d + 64]);
  const float p1 = ldw(rote, rbase + d, isf);
  const float p2 = ldw(rote, rbase + d + 64, isf);
  q[qbase + d]      = f2bf(q1 * cosf(p1) - q2 * sinf(p1));
  q[qbase + d + 64] = f2bf(q2 * cosf(p2) + q1 * sinf(p2));
}

// Barrier-free flash: K and V^T both pre-rotated/pre-transposed bf16 in global.
// Each 64-lane wave owns 16 q-rows; only LDS use is the per-warp P transpose.
__global__ __launch_bounds__(256) void flash_k(const u16* __restrict__ qrot,
                                               const u16* __restrict__ krot,
                                               const u16* __restrict__ vt,
                                               u16* __restrict__ aout)
{
  __shared__ __align__(16) u16 Pl[4][16 * 40];   // stride 40 u16: conflict-free transpose
  const int flat = blockIdx.x;
  const int it = 15 - (flat >> 6);               // heavy tiles dispatched first
  const int bh = flat & 63;                      // XCD pinned by bh%8
  const int b = bh >> 4, h = bh & 15;
  const int tid = threadIdx.x, lane = tid & 63, w = tid >> 6;
  const int l15 = lane & 15, quad = lane >> 4;
  const u16* __restrict__ kr = krot + (size_t)bh * JSEQ * DHEAD;      // [j][d]
  const u16* __restrict__ vr = vt + (size_t)bh * DHEAD * JSEQ;        // [d][j]
  const int ibase = it * 64 + w * 16;

  short8 qf[4];
  #pragma unroll
  for (int ds = 0; ds < 4; ++ds)
    qf[ds] = *(const short8*)(qrot +
        ((size_t)bh * NSEQ + ibase + l15) * DHEAD + ds * 32 + quad * 8);

  floatx4 o[8];
  #pragma unroll
  for (int dt = 0; dt < 8; ++dt) o[dt] = (floatx4){0.f, 0.f, 0.f, 0.f};
  float m_r[4] = {-1e30f, -1e30f, -1e30f, -1e30f};
  float l_r[4] = {0.f, 0.f, 0.f, 0.f};

  // warp w needs j <= ibase+15+1024 -> per-warp tile count
  const int jend = it * 64 + ((w * 16 + 1040 + 31) & ~31);

  for (int j0 = 0; j0 < jend; j0 += 32) {
    // issue V fragment loads first (consumed last -> latency hidden under QK+softmax)
    short8 vf[8];
    #pragma unroll
    for (int dt = 0; dt < 8; ++dt)
      vf[dt] = *(const short8*)(vr + (size_t)(dt * 16 + l15) * JSEQ + j0 + quad * 8);
    short8 kf[2][4];
    #pragma unroll
    for (int nt = 0; nt < 2; ++nt)
      #pragma unroll
      for (int ds = 0; ds < 4; ++ds)
        kf[nt][ds] = *(const short8*)(kr + (size_t)(j0 + nt * 16 + l15) * DHEAD + ds * 32 + quad * 8);

    floatx4 s[2];
    s[0] = (floatx4){0.f, 0.f, 0.f, 0.f};
    s[1] = (floatx4){0.f, 0.f, 0.f, 0.f};
    __builtin_amdgcn_s_setprio(1);
    #pragma unroll
    for (int nt = 0; nt < 2; ++nt)
      #pragma unroll
      for (int ds = 0; ds < 4; ++ds)
        s[nt] = __builtin_amdgcn_mfma_f32_16x16x32_bf16(qf[ds], kf[nt][ds], s[nt], 0, 0, 0);
    __builtin_amdgcn_s_setprio(0);

    float sv[2][4];
    #pragma unroll
    for (int nt = 0; nt < 2; ++nt)
      #pragma unroll
      for (int r = 0; r < 4; ++r) {
        const int ig = ibase + quad * 4 + r;
        const int jg = j0 + nt * 16 + l15;
        const float xx = s[nt][r] * 0.08838834764831845f;
        sv[nt][r] = (jg > ig + 1024) ? -1e30f : xx;
      }
    float mx4[4];
    #pragma unroll
    for (int r = 0; r < 4; ++r) {
      float mx = fmaxf(sv[0][r], sv[1][r]);
      #pragma unroll
      for (int off = 1; off < 16; off <<= 1) mx = fmaxf(mx, __shfl_xor(mx, off, 16));
      mx4[r] = mx;
    }
    // defer-max: skip O/l rescale unless some row max grew by > 8
    const bool need = (mx4[0] > m_r[0] + 8.f) || (mx4[1] > m_r[1] + 8.f) ||
                      (mx4[2] > m_r[2] + 8.f) || (mx4[3] > m_r[3] + 8.f);
    if (__ballot(need)) {
      #pragma unroll
      for (int r = 0; r < 4; ++r) {
        const float mn = fmaxf(m_r[r], mx4[r]);
        const float a = __expf(m_r[r] - mn);
        m_r[r] = mn;
        l_r[r] *= a;
        #pragma unroll
        for (int dt = 0; dt < 8; ++dt) o[dt][r] *= a;
      }
    }
    #pragma unroll
    for (int r = 0; r < 4; ++r) {
      const float p0 = __expf(sv[0][r] - m_r[r]);
      const float p1 = __expf(sv[1][r] - m_r[r]);
      Pl[w][(quad * 4 + r) * 40 + l15]      = f2bf(p0);
      Pl[w][(quad * 4 + r) * 40 + 16 + l15] = f2bf(p1);
      float ps = p0 + p1;
      #pragma unroll
      for (int off = 1; off < 16; off <<= 1) ps += __shfl_xor(ps, off, 16);
      l_r[r] += ps;
    }
    const short8 pf = *(const short8*)&Pl[w][l15 * 40 + quad * 8];
    __builtin_amdgcn_s_setprio(1);
    #pragma unroll
    for (int dt = 0; dt < 8; ++dt)
      o[dt] = __builtin_amdgcn_mfma_f32_16x16x32_bf16(pf, vf[dt], o[dt], 0, 0, 0);
    __builtin_amdgcn_s_setprio(0);
  }

  float inv[4];
  #pragma unroll
  for (int r = 0; r < 4; ++r) inv[r] = (l_r[r] > 0.f) ? 1.0f / l_r[r] : 0.f;
  #pragma unroll
  for (int dt = 0; dt < 8; ++dt)
    #pragma unroll
    for (int r = 0; r < 4; ++r) {
      const int row = b * NSEQ + ibase + quad * 4 + r;
      const int col = h * DHEAD + dt * 16 + l15;
      aout[(size_t)row * DIM + col] = f2bf(o[dt][r] * inv[r]);
    }
}

extern "C" void kernel_launch(void* const* d_in, const int* in_sizes, int n_in,
                              void* d_out, int out_size, void* d_ws, size_t ws_size,
                              hipStream_t stream)
{
  const void* x     = d_in[0];
  const void* cache = d_in[1];
  const void* rote  = d_in[2];
  const void* normw = d_in[4];
  const void* wqkv  = d_in[5];
  const void* wout  = d_in[6];

  int* flag = (int*)d_ws;
  u16* bufA = (u16*)((char*)d_ws + 256);                                   // 16.8 MB: xn then attn
  u16* regB = (u16*)((char*)d_ws + 256 + (size_t)16777216);                // 33.6 MB: wqkvT -> krot -> woutT
  u16* vt   = (u16*)((char*)d_ws + 256 + (size_t)16777216 + 33554432);     // 33.6 MB: V^T bf16
  u16* xn   = bufA;
  u16* attn = bufA;
  u16* krot = regB;
  u16* qrot = (u16*)d_out;                 // bf16 scratch inside outp region

  detect_k<<<1, 1, 0, stream>>>(normw, flag);
  // weights prep: w_qkv -> [NIN][DIM] bf16 in regB
  prep_w_k<<<dim3(NIN / 64, DIM / 64), 256, 0, stream>>>(wqkv, regB, flag, DIM, NIN);
  rmsnorm_k<<<BB * NSEQ, 256, 0, stream>>>(x, normw, xn, flag);
  gemm_tn<<<dim3(NIN / 128, (BB * NSEQ) / 128), 256, 0, stream>>>(
      xn, regB, nullptr, qrot, d_out, flag, BB * NSEQ, NIN, DIM, 1);
  copy_cache_k<<<16384, 256, 0, stream>>>(cache, d_out, flag);
  k_rot_k<<<32768, 256, 0, stream>>>(d_out, rote, krot, flag);   // overwrites wqkvT (done)
  v_tr_k<<<dim3(JSEQ / 64, DHEAD / 64, BB * HEADS), 256, 0, stream>>>(d_out, vt, flag);
  q_rot_k<<<16384, 256, 0, stream>>>(qrot, rote, flag);
  flash_k<<<dim3(16 * HEADS * BB), 256, 0, stream>>>(qrot, krot, vt, attn);
  // w_out prep into regB (krot no longer needed)
  prep_w_k<<<dim3(DIM / 64, DIM / 64), 256, 0, stream>>>(wout, regB, flag, DIM, DIM);
  gemm_tn<<<dim3(DIM / 128, (BB * NSEQ) / 128), 256, 0, stream>>>(
      attn, regB, d_out, nullptr, nullptr, flag, BB * NSEQ, DIM, DIM, 0);
}

// Round 4
// 763.611 us; speedup vs baseline: 1.1956x; 1.1956x over previous
//
#include <hip/hip_runtime.h>
#include <hip/hip_bf16.h>
#include <stdint.h>

typedef unsigned short u16;
typedef __attribute__((ext_vector_type(8))) short short8;
typedef __attribute__((ext_vector_type(4))) float floatx4;

#define DIM    2048
#define HEADS  16
#define DHEAD  128
#define BB     4
#define NSEQ   1024
#define JSEQ   2048
#define NIN    6144
#define KVOFF  ((size_t)8388608)   // cached_kv element offset inside d_out

__device__ __forceinline__ float bf2f(u16 u) {
  union { uint32_t u; float f; } c; c.u = ((uint32_t)u) << 16; return c.f;
}
__device__ __forceinline__ u16 f2bf(float f) {
  union { float f; uint32_t u; } c; c.f = f;
  uint32_t u = c.u;
  return (u16)((u + 0x7fffu + ((u >> 16) & 1u)) >> 16);
}
__device__ __forceinline__ float ldw(const void* p, size_t i, int isf) {
  if (isf) return ((const float*)p)[i];
  return bf2f(((const u16*)p)[i]);
}
__device__ __forceinline__ void stw(void* p, size_t i, int isf, float v) {
  if (isf) ((float*)p)[i] = v;
  else     ((u16*)p)[i] = f2bf(v);
}

// async global->LDS, 16B per lane. LDS dest must be wave-uniform base (+lane*16 implicit).
__device__ __forceinline__ void gload16(const u16* g, u16* l) {
  __builtin_amdgcn_global_load_lds(
      reinterpret_cast<const __attribute__((address_space(1))) void*>(
          reinterpret_cast<uintptr_t>(g)),
      reinterpret_cast<__attribute__((address_space(3))) void*>(
          reinterpret_cast<uintptr_t>(l)),
      16, 0, 0);
}

__global__ void detect_k(const void* normw, int* flag) {
  uint32_t v = *(const uint32_t*)normw;
  *flag = ((v & 0xFFFFu) == 0u) ? 1 : 0;   // fp32 1.0f low16==0; bf16 pair low16=0x3F80
}

__global__ __launch_bounds__(256) void rmsnorm_k(const void* __restrict__ x,
                                                 const void* __restrict__ w,
                                                 u16* __restrict__ xn,
                                                 const int* __restrict__ flag)
{
  const int isf = *flag;
  const int row = blockIdx.x;
  const int t = threadIdx.x;
  const size_t base = (size_t)row * DIM + t * 8;
  float f[8]; float ss = 0.f;
  #pragma unroll
  for (int i = 0; i < 8; ++i) { f[i] = ldw(x, base + i, isf); ss += f[i] * f[i]; }
  #pragma unroll
  for (int off = 1; off < 64; off <<= 1) ss += __shfl_xor(ss, off, 64);
  __shared__ float red[4];
  if ((t & 63) == 0) red[t >> 6] = ss;
  __syncthreads();
  float tot = red[0] + red[1] + red[2] + red[3];
  float rs = rsqrtf(tot * (1.0f / DIM) + 1.1920929e-7f);
  #pragma unroll
  for (int i = 0; i < 8; ++i)
    xn[base + i] = f2bf(f[i] * rs * ldw(w, (size_t)(t * 8 + i), isf));
}

// Transpose + convert weights: W[K][N] (wire) -> WT[N][K] (bf16). 64x64 tiles.
__global__ __launch_bounds__(256) void prep_w_k(const void* __restrict__ W,
                                                u16* __restrict__ WT,
                                                const int* __restrict__ flag,
                                                int K, int N)
{
  __shared__ u16 T[64][72];
  const int isf = *flag;
  const int n0 = blockIdx.x * 64, k0 = blockIdx.y * 64;
  const int tid = threadIdx.x;
  const int r = tid >> 2;           // 0..63
  const int c = (tid & 3) * 16;     // 0,16,32,48
  {
    u16 tmp[16];
    if (isf) {
      const float4* p = (const float4*)((const float*)W + (size_t)(k0 + r) * N + n0 + c);
      #pragma unroll
      for (int cc = 0; cc < 4; ++cc) {
        const float4 fv = p[cc];
        tmp[cc * 4 + 0] = f2bf(fv.x);
        tmp[cc * 4 + 1] = f2bf(fv.y);
        tmp[cc * 4 + 2] = f2bf(fv.z);
        tmp[cc * 4 + 3] = f2bf(fv.w);
      }
    } else {
      const uint4* p = (const uint4*)((const u16*)W + (size_t)(k0 + r) * N + n0 + c);
      *(uint4*)&tmp[0] = p[0];
      *(uint4*)&tmp[8] = p[1];
    }
    #pragma unroll
    for (int e = 0; e < 16; ++e) T[r][c + e] = tmp[e];
  }
  __syncthreads();
  {
    u16 tmp[16];
    #pragma unroll
    for (int e = 0; e < 16; ++e) tmp[e] = T[c + e][r];
    uint4* q = (uint4*)(WT + (size_t)(n0 + r) * K + k0 + c);
    q[0] = *(const uint4*)&tmp[0];
    q[1] = *(const uint4*)&tmp[8];
  }
}

// V[bh][j][d] (wire, inside dout) -> VT[bh][d][j] (bf16). 64x64 tiles.
__global__ __launch_bounds__(256) void v_tr_k(const void* __restrict__ dout,
                                              u16* __restrict__ vt,
                                              const int* __restrict__ flag)
{
  __shared__ u16 T[64][72];
  const int isf = *flag;
  const int j0 = blockIdx.x * 64;        // 0..2047
  const int d0 = blockIdx.y * 64;        // 0,64
  const int bh = blockIdx.z;             // 0..63
  const int b = bh >> 4, h = bh & 15;
  const size_t vbase = KVOFF + (((size_t)b * 2 + 1) * HEADS + h) * JSEQ * DHEAD;
  const int tid = threadIdx.x;
  const int r = tid >> 2;
  const int c = (tid & 3) * 16;
  {
    u16 tmp[16];
    if (isf) {
      const float4* p = (const float4*)((const float*)dout + vbase + (size_t)(j0 + r) * DHEAD + d0 + c);
      #pragma unroll
      for (int cc = 0; cc < 4; ++cc) {
        const float4 fv = p[cc];
        tmp[cc * 4 + 0] = f2bf(fv.x);
        tmp[cc * 4 + 1] = f2bf(fv.y);
        tmp[cc * 4 + 2] = f2bf(fv.z);
        tmp[cc * 4 + 3] = f2bf(fv.w);
      }
    } else {
      const uint4* p = (const uint4*)((const u16*)dout + vbase + (size_t)(j0 + r) * DHEAD + d0 + c);
      *(uint4*)&tmp[0] = p[0];
      *(uint4*)&tmp[8] = p[1];
    }
    #pragma unroll
    for (int e = 0; e < 16; ++e) T[r][c + e] = tmp[e];
  }
  __syncthreads();
  {
    u16 tmp[16];
    #pragma unroll
    for (int e = 0; e < 16; ++e) tmp[e] = T[c + e][r];
    uint4* q = (uint4*)(vt + ((size_t)bh * DHEAD + d0 + r) * JSEQ + j0 + c);
    q[0] = *(const uint4*)&tmp[0];
    q[1] = *(const uint4*)&tmp[8];
  }
}

// C = A[M,K](bf16) x BT[N,K](bf16)^T. m97 structure + XCD-aware tile swizzle.
// mode 0: C -> obuf (wire). mode 1: qkv split.
__global__ __launch_bounds__(256) void gemm_tn(const u16* __restrict__ A,
                                               const u16* __restrict__ BT,
                                               void* __restrict__ obuf,
                                               u16* __restrict__ qbuf,
                                               void* __restrict__ dout,
                                               const int* __restrict__ flag,
                                               int M, int N, int K, int mode)
{
  __shared__ __align__(16) u16 As[128 * 32];
  __shared__ __align__(16) u16 Bs[128 * 32];
  const int isf = *flag;
  const int tid = threadIdx.x;
  const int lane = tid & 63;
  const int w = tid >> 6;
  const int wm = w & 1, wn = w >> 1;
  const int l15 = lane & 15, quad = lane >> 4;
  // XCD-aware bijective swizzle (nwg divisible by 8 for both launches)
  const int nwg = gridDim.x * gridDim.y;
  int lin = blockIdx.y * gridDim.x + blockIdx.x;
  lin = (lin & 7) * (nwg >> 3) + (lin >> 3);
  const int m0 = (lin / gridDim.x) * 128, n0 = (lin % gridDim.x) * 128;

  const int srow = tid >> 2;          // 0..63
  const int scol = (tid & 3) * 8;     // 0,8,16,24
  const u16* ag0 = A  + (size_t)(m0 + srow) * K + scol;
  const u16* ag1 = A  + (size_t)(m0 + 64 + srow) * K + scol;
  const u16* bg0 = BT + (size_t)(n0 + srow) * K + scol;
  const u16* bg1 = BT + (size_t)(n0 + 64 + srow) * K + scol;
  u16* const al = As + w * 512;       // wave-uniform LDS base (+lane*16B implicit)
  u16* const bl = Bs + w * 512;

  floatx4 acc[4][4];
  #pragma unroll
  for (int i = 0; i < 4; ++i)
    #pragma unroll
    for (int j = 0; j < 4; ++j) acc[i][j] = (floatx4){0.f, 0.f, 0.f, 0.f};

  for (int k0 = 0; k0 < K; k0 += 32) {
    __syncthreads();
    gload16(ag0 + k0, al);
    gload16(ag1 + k0, al + 2048);
    gload16(bg0 + k0, bl);
    gload16(bg1 + k0, bl + 2048);
    __syncthreads();

    short8 af[4], bfr[4];
    #pragma unroll
    for (int mt = 0; mt < 4; ++mt)
      af[mt] = *(const short8*)&As[(wm * 64 + mt * 16 + l15) * 32 + quad * 8];
    #pragma unroll
    for (int nt = 0; nt < 4; ++nt)
      bfr[nt] = *(const short8*)&Bs[(wn * 64 + nt * 16 + l15) * 32 + quad * 8];
    __builtin_amdgcn_s_setprio(1);
    #pragma unroll
    for (int mt = 0; mt < 4; ++mt)
      #pragma unroll
      for (int nt = 0; nt < 4; ++nt)
        acc[mt][nt] = __builtin_amdgcn_mfma_f32_16x16x32_bf16(af[mt], bfr[nt], acc[mt][nt], 0, 0, 0);
    __builtin_amdgcn_s_setprio(0);
  }

  #pragma unroll
  for (int mt = 0; mt < 4; ++mt)
    #pragma unroll
    for (int nt = 0; nt < 4; ++nt) {
      const int col = n0 + wn * 64 + nt * 16 + l15;
      #pragma unroll
      for (int r = 0; r < 4; ++r) {
        const int row = m0 + wm * 64 + mt * 16 + quad * 4 + r;
        const float v = acc[mt][nt][r];
        if (mode == 0) {
          stw(obuf, (size_t)row * N + col, isf, v);
        } else {
          const int b = row >> 10, i = row & 1023;
          const int sec = col >> 11, within = col & 2047;
          const int h = within >> 7, d = within & 127;
          if (sec == 0) {
            qbuf[(((size_t)(b * HEADS + h)) * NSEQ + i) * DHEAD + d] = f2bf(v);
          } else {
            const size_t idx = KVOFF +
              ((((size_t)b * 2 + (sec - 1)) * HEADS + h) * JSEQ + NSEQ + i) * DHEAD + d;
            stw(dout, idx, isf, v);
          }
        }
      }
    }
}

__global__ __launch_bounds__(256) void copy_cache_k(const void* __restrict__ cache,
                                                    void* __restrict__ dout,
                                                    const int* __restrict__ flag)
{
  const int isf = *flag;
  const size_t t = ((size_t)blockIdx.x * 256 + threadIdx.x) * 4;   // element index
  const size_t sh = t >> 17;
  const size_t rem = t & 131071;
  const size_t dst = KVOFF + (sh << 18) + rem;
  if (isf) *(float4*)((float*)dout + dst) = *(const float4*)((const float*)cache + t);
  else     *(uint2*)((u16*)dout + dst)    = *(const uint2*)((const u16*)cache + t);
}

// One-shot: rotate full K (cached + new) into bf16 krot[b][h][JSEQ][DHEAD].
__global__ __launch_bounds__(256) void k_rot_k(const void* __restrict__ dout,
                                               const void* __restrict__ rote,
                                               u16* __restrict__ krot,
                                               const int* __restrict__ flag)
{
  const int isf = *flag;
  const size_t t = (size_t)blockIdx.x * 256 + threadIdx.x;   // 8,388,608
  const int d = (int)(t & 63);
  const size_t row = t >> 6;                    // bh*JSEQ + j
  const int j = (int)(row & (JSEQ - 1));
  const size_t bh = row >> 11;                  // b*16 + h
  const size_t kb = KVOFF + (((bh >> 4) * 2 * HEADS + (bh & 15)) * (size_t)JSEQ + j) * DHEAD;
  const float k1 = ldw(dout, kb + d, isf);
  const float k2 = ldw(dout, kb + d + 64, isf);
  const size_t rb = (size_t)j * DHEAD;
  const float p1 = ldw(rote, rb + d, isf);
  const float p2 = ldw(rote, rb + d + 64, isf);
  krot[row * DHEAD + d]      = f2bf(k1 * cosf(p1) - k2 * sinf(p1));
  krot[row * DHEAD + d + 64] = f2bf(k2 * cosf(p2) + k1 * sinf(p2));
}

__global__ __launch_bounds__(256) void q_rot_k(u16* __restrict__ q,
                                               const void* __restrict__ rote,
                                               const int* __restrict__ flag)
{
  const int isf = *flag;
  const size_t t = (size_t)blockIdx.x * 256 + threadIdx.x;   // 4,194,304
  const int d = (int)(t & 63);
  const size_t row = t >> 6;
  const int i = (int)(row & 1023);
  const size_t qbase = row * DHEAD;
  const size_t rbase = (size_t)(NSEQ + i) * DHEAD;
  const float q1 = bf2f(q[qbase + d]);
  const float q2 = bf2f(q[qbase + d + 64]);
  const float p1 = ldw(rote, rbase + d, isf);
  const float p2 = ldw(rote, rbase + d + 64, isf);
  q[qbase + d]      = f2bf(q1 * cosf(p1) - q2 * sinf(p1));
  q[qbase + d + 64] = f2bf(q2 * cosf(p2) + q1 * sinf(p2));
}

// One 32-j tile for a 32-row wave (two 16-row subtiles sharing K/V fragments).
// Issues V loads + next-tile K prefetch first; l accumulated via ones-MFMA.
__device__ __forceinline__ void att_tile(
    int j0, int jn, int ibase, int l15, int quad,
    const u16* __restrict__ kr, const u16* __restrict__ vr,
    u16* __restrict__ Plw,
    const short8 (&qf)[2][4], const short8 (&kf)[2][4], short8 (&kn)[2][4],
    const short8 ones,
    floatx4 (&o)[2][8], floatx4 (&lacc)[2], float (&m_r)[2][4])
{
  // V fragments for this tile (consumed at PV -> full-tile slack)
  short8 vf[8];
  #pragma unroll
  for (int dt = 0; dt < 8; ++dt)
    vf[dt] = *(const short8*)(vr + (size_t)(dt * 16 + l15) * JSEQ + j0 + quad * 8);
  // prefetch next tile's K fragments (consumed next tile -> full-tile slack)
  #pragma unroll
  for (int nt = 0; nt < 2; ++nt)
    #pragma unroll
    for (int ds = 0; ds < 4; ++ds)
      kn[nt][ds] = *(const short8*)(kr + (size_t)(jn + nt * 16 + l15) * DHEAD + ds * 32 + quad * 8);

  // QK^T for both subtiles with shared K
  floatx4 s[2][2];
  #pragma unroll
  for (int t = 0; t < 2; ++t) {
    s[t][0] = (floatx4){0.f, 0.f, 0.f, 0.f};
    s[t][1] = (floatx4){0.f, 0.f, 0.f, 0.f};
  }
  __builtin_amdgcn_s_setprio(1);
  #pragma unroll
  for (int nt = 0; nt < 2; ++nt)
    #pragma unroll
    for (int ds = 0; ds < 4; ++ds) {
      s[0][nt] = __builtin_amdgcn_mfma_f32_16x16x32_bf16(qf[0][ds], kf[nt][ds], s[0][nt], 0, 0, 0);
      s[1][nt] = __builtin_amdgcn_mfma_f32_16x16x32_bf16(qf[1][ds], kf[nt][ds], s[1][nt], 0, 0, 0);
    }
  __builtin_amdgcn_s_setprio(0);

  #pragma unroll
  for (int t = 0; t < 2; ++t) {
    float sv[2][4];
    #pragma unroll
    for (int nt = 0; nt < 2; ++nt)
      #pragma unroll
      for (int r = 0; r < 4; ++r) {
        const int ig = ibase + t * 16 + quad * 4 + r;
        const int jg = j0 + nt * 16 + l15;
        const float xx = s[t][nt][r] * 0.08838834764831845f;
        sv[nt][r] = (jg > ig + 1024) ? -1e30f : xx;
      }
    float mx4[4];
    #pragma unroll
    for (int r = 0; r < 4; ++r) {
      float mx = fmaxf(sv[0][r], sv[1][r]);
      #pragma unroll
      for (int off = 1; off < 16; off <<= 1) mx = fmaxf(mx, __shfl_xor(mx, off, 16));
      mx4[r] = mx;
    }
    // defer-max: rescale only when some row max grew by > 8
    bool need = false;
    #pragma unroll
    for (int r = 0; r < 4; ++r) need = need || (mx4[r] > m_r[t][r] + 8.f);
    if (__ballot(need)) {
      #pragma unroll
      for (int r = 0; r < 4; ++r) {
        const float mn = fmaxf(m_r[t][r], mx4[r]);
        const float a = __expf(m_r[t][r] - mn);
        m_r[t][r] = mn;
        lacc[t][r] *= a;
        #pragma unroll
        for (int dt = 0; dt < 8; ++dt) o[t][dt][r] *= a;
      }
    }
    #pragma unroll
    for (int r = 0; r < 4; ++r) {
      const float p0 = __expf(sv[0][r] - m_r[t][r]);
      const float p1 = __expf(sv[1][r] - m_r[t][r]);
      Plw[t * 640 + (quad * 4 + r) * 40 + l15]      = f2bf(p0);
      Plw[t * 640 + (quad * 4 + r) * 40 + 16 + l15] = f2bf(p1);
    }
  }

  const short8 pf0 = *(const short8*)(Plw + l15 * 40 + quad * 8);
  const short8 pf1 = *(const short8*)(Plw + 640 + l15 * 40 + quad * 8);
  __builtin_amdgcn_s_setprio(1);
  lacc[0] = __builtin_amdgcn_mfma_f32_16x16x32_bf16(pf0, ones, lacc[0], 0, 0, 0);
  lacc[1] = __builtin_amdgcn_mfma_f32_16x16x32_bf16(pf1, ones, lacc[1], 0, 0, 0);
  #pragma unroll
  for (int dt = 0; dt < 8; ++dt) {
    o[0][dt] = __builtin_amdgcn_mfma_f32_16x16x32_bf16(pf0, vf[dt], o[0][dt], 0, 0, 0);
    o[1][dt] = __builtin_amdgcn_mfma_f32_16x16x32_bf16(pf1, vf[dt], o[1][dt], 0, 0, 0);
  }
  __builtin_amdgcn_s_setprio(0);
}

// Barrier-free flash, 32 q-rows per wave. Grid: 8 it x 64 bh.
__global__ __launch_bounds__(256, 2) void flash_k(const u16* __restrict__ qrot,
                                                  const u16* __restrict__ krot,
                                                  const u16* __restrict__ vt,
                                                  u16* __restrict__ aout)
{
  __shared__ __align__(16) u16 Pl[4][2][640];
  const int flat = blockIdx.x;
  const int it = flat >> 6;                      // 0..7
  const int bh = flat & 63;                      // XCD pinned by bh%8
  const int b = bh >> 4, h = bh & 15;
  const int tid = threadIdx.x, lane = tid & 63, w = tid >> 6;
  const int l15 = lane & 15, quad = lane >> 4;
  const u16* __restrict__ kr = krot + (size_t)bh * JSEQ * DHEAD;      // [j][d]
  const u16* __restrict__ vr = vt + (size_t)bh * DHEAD * JSEQ;        // [d][j]
  const int ibase = it * 128 + w * 32;
  u16* const Plw = &Pl[w][0][0];

  short8 qf[2][4];
  #pragma unroll
  for (int t = 0; t < 2; ++t)
    #pragma unroll
    for (int ds = 0; ds < 4; ++ds)
      qf[t][ds] = *(const short8*)(qrot +
          ((size_t)bh * NSEQ + ibase + t * 16 + l15) * DHEAD + ds * 32 + quad * 8);

  floatx4 o[2][8];
  #pragma unroll
  for (int t = 0; t < 2; ++t)
    #pragma unroll
    for (int dt = 0; dt < 8; ++dt) o[t][dt] = (floatx4){0.f, 0.f, 0.f, 0.f};
  floatx4 lacc[2];
  lacc[0] = (floatx4){0.f, 0.f, 0.f, 0.f};
  lacc[1] = (floatx4){0.f, 0.f, 0.f, 0.f};
  float m_r[2][4];
  #pragma unroll
  for (int t = 0; t < 2; ++t)
    #pragma unroll
    for (int r = 0; r < 4; ++r) m_r[t][r] = -1e30f;

  short8 ones;
  #pragma unroll
  for (int e = 0; e < 8; ++e) ones[e] = (short)0x3F80;

  const int jend  = ibase + 1056;          // exact causal bound, multiple of 32
  const int jend2 = (jend + 63) & ~63;     // rounded for unroll-2 (extra tile fully masked)

  short8 kfA[2][4], kfB[2][4];
  #pragma unroll
  for (int nt = 0; nt < 2; ++nt)
    #pragma unroll
    for (int ds = 0; ds < 4; ++ds)
      kfA[nt][ds] = *(const short8*)(kr + (size_t)(nt * 16 + l15) * DHEAD + ds * 32 + quad * 8);

  for (int j0 = 0; j0 < jend2; j0 += 64) {
    att_tile(j0,      j0 + 32, ibase, l15, quad, kr, vr, Plw, qf, kfA, kfB, ones, o, lacc, m_r);
    att_tile(j0 + 32, j0 + 64, ibase, l15, quad, kr, vr, Plw, qf, kfB, kfA, ones, o, lacc, m_r);
  }

  #pragma unroll
  for (int t = 0; t < 2; ++t) {
    float inv[4];
    #pragma unroll
    for (int r = 0; r < 4; ++r) inv[r] = (lacc[t][r] > 0.f) ? 1.0f / lacc[t][r] : 0.f;
    #pragma unroll
    for (int dt = 0; dt < 8; ++dt)
      #pragma unroll
      for (int r = 0; r < 4; ++r) {
        const int row = b * NSEQ + ibase + t * 16 + quad * 4 + r;
        const int col = h * DHEAD + dt * 16 + l15;
        aout[(size_t)row * DIM + col] = f2bf(o[t][dt][r] * inv[r]);
      }
  }
}

extern "C" void kernel_launch(void* const* d_in, const int* in_sizes, int n_in,
                              void* d_out, int out_size, void* d_ws, size_t ws_size,
                              hipStream_t stream)
{
  const void* x     = d_in[0];
  const void* cache = d_in[1];
  const void* rote  = d_in[2];
  const void* normw = d_in[4];
  const void* wqkv  = d_in[5];
  const void* wout  = d_in[6];

  int* flag = (int*)d_ws;
  u16* bufA = (u16*)((char*)d_ws + 256);                                   // 16.8 MB: xn then attn
  u16* regB = (u16*)((char*)d_ws + 256 + (size_t)16777216);                // 33.6 MB: wqkvT -> krot -> woutT
  u16* vt   = (u16*)((char*)d_ws + 256 + (size_t)16777216 + 33554432);     // 33.6 MB: V^T bf16
  u16* xn   = bufA;
  u16* attn = bufA;
  u16* krot = regB;
  u16* qrot = (u16*)d_out;                 // bf16 scratch inside outp region

  detect_k<<<1, 1, 0, stream>>>(normw, flag);
  // weights prep: w_qkv -> [NIN][DIM] bf16 in regB
  prep_w_k<<<dim3(NIN / 64, DIM / 64), 256, 0, stream>>>(wqkv, regB, flag, DIM, NIN);
  rmsnorm_k<<<BB * NSEQ, 256, 0, stream>>>(x, normw, xn, flag);
  gemm_tn<<<dim3(NIN / 128, (BB * NSEQ) / 128), 256, 0, stream>>>(
      xn, regB, nullptr, qrot, d_out, flag, BB * NSEQ, NIN, DIM, 1);
  copy_cache_k<<<16384, 256, 0, stream>>>(cache, d_out, flag);
  k_rot_k<<<32768, 256, 0, stream>>>(d_out, rote, krot, flag);   // overwrites wqkvT (done)
  v_tr_k<<<dim3(JSEQ / 64, DHEAD / 64, BB * HEADS), 256, 0, stream>>>(d_out, vt, flag);
  q_rot_k<<<16384, 256, 0, stream>>>(qrot, rote, flag);
  flash_k<<<dim3(8 * 64), 256, 0, stream>>>(qrot, krot, vt, attn);
  // w_out prep into regB (krot no longer needed)
  prep_w_k<<<dim3(DIM / 64, DIM / 64), 256, 0, stream>>>(wout, regB, flag, DIM, DIM);
  gemm_tn<<<dim3(DIM / 128, (BB * NSEQ) / 128), 256, 0, stream>>>(
      attn, regB, d_out, nullptr, nullptr, flag, BB * NSEQ, DIM, DIM, 0);
}